// Round 8
// baseline (311.213 us; speedup 1.0000x reference)
//
#include <hip/hip_runtime.h>
#include <math.h>

// Emulate a dtype-faithful numpy float32 mirror of the jax reference:
// - no FMA anywhere (contract off; np mul/add are separate ufuncs)
// - 9-tap conv accumulated in numpy pairwise_sum order for n=9:
//     ((q0+q1)+(q2+q3))+((q4+q5)+(q6+q7)) then += q8
// - weight sum k.sum() in the same pairwise-tail order
// - sequential f32 cumsums (np.cumsum), first-occurrence argmax
#pragma clang fp contract(off)

struct GaussW { float w[9]; };

__global__ __launch_bounds__(256) void init_kernel(unsigned* __restrict__ hist,
                                                   unsigned* __restrict__ minmax, int nimg) {
    #pragma clang fp contract(off)
    int i = blockIdx.x * 256 + threadIdx.x;
    if (i < nimg * 256) hist[i] = 0u;
    if (i < nimg) { minmax[2 * i] = 0x7F800000u; minmax[2 * i + 1] = 0u; }
}

// thermal = clip(x0*0.5+0.5) f32; 9-tap separable Gaussian (edge clamp) f32,
// numpy pairwise tap order, f32 vertical intermediate. Per-image min/max via
// uint atomics (all values >= 0 so float bits order as uints).
__global__ __launch_bounds__(256) void blur_kernel(const float* __restrict__ x,
                                                   float* __restrict__ blurred,
                                                   unsigned* __restrict__ minmax, GaussW gw) {
    #pragma clang fp contract(off)
    __shared__ float s_in[72][72];   // rows r0-4..r0+67, cols c0-4..c0+67
    __shared__ float s_vb[64][72];   // vertically blurred, cols c0-4..c0+67
    const int tid = threadIdx.x;
    const int b = blockIdx.z;
    const int r0 = blockIdx.y * 64, c0 = blockIdx.x * 64;
    const float* img0 = x + (size_t)b * 4 * 262144;

    for (int i = tid; i < 72 * 72; i += 256) {
        int r = i / 72, c = i - r * 72;
        int gr = min(max(r0 + r - 4, 0), 511);
        int gc = min(max(c0 + c - 4, 0), 511);
        float v = img0[gr * 512 + gc];
        s_in[r][c] = fminf(fmaxf(v * 0.5f + 0.5f, 0.0f), 1.0f);
    }
    __syncthreads();
    for (int i = tid; i < 64 * 72; i += 256) {
        int r = i / 72, c = i - r * 72;
        float q0 = s_in[r + 0][c] * gw.w[0];
        float q1 = s_in[r + 1][c] * gw.w[1];
        float q2 = s_in[r + 2][c] * gw.w[2];
        float q3 = s_in[r + 3][c] * gw.w[3];
        float q4 = s_in[r + 4][c] * gw.w[4];
        float q5 = s_in[r + 5][c] * gw.w[5];
        float q6 = s_in[r + 6][c] * gw.w[6];
        float q7 = s_in[r + 7][c] * gw.w[7];
        float q8 = s_in[r + 8][c] * gw.w[8];
        float acc = ((q0 + q1) + (q2 + q3)) + ((q4 + q5) + (q6 + q7));
        acc = acc + q8;
        s_vb[r][c] = acc;
    }
    __syncthreads();
    float lmin = 1e30f, lmax = -1e30f;
    float* bimg = blurred + (size_t)b * 262144;
    for (int i = tid; i < 64 * 64; i += 256) {
        int r = i >> 6, c = i & 63;
        float q0 = s_vb[r][c + 0] * gw.w[0];
        float q1 = s_vb[r][c + 1] * gw.w[1];
        float q2 = s_vb[r][c + 2] * gw.w[2];
        float q3 = s_vb[r][c + 3] * gw.w[3];
        float q4 = s_vb[r][c + 4] * gw.w[4];
        float q5 = s_vb[r][c + 5] * gw.w[5];
        float q6 = s_vb[r][c + 6] * gw.w[6];
        float q7 = s_vb[r][c + 7] * gw.w[7];
        float q8 = s_vb[r][c + 8] * gw.w[8];
        float acc = ((q0 + q1) + (q2 + q3)) + ((q4 + q5) + (q6 + q7));
        acc = acc + q8;
        bimg[(r0 + r) * 512 + (c0 + c)] = acc;
        lmin = fminf(lmin, acc);
        lmax = fmaxf(lmax, acc);
    }
    for (int off = 32; off >= 1; off >>= 1) {
        lmin = fminf(lmin, __shfl_down(lmin, off));
        lmax = fmaxf(lmax, __shfl_down(lmax, off));
    }
    __shared__ float smin[4], smax[4];
    int wave = tid >> 6, lane = tid & 63;
    if (lane == 0) { smin[wave] = lmin; smax[wave] = lmax; }
    __syncthreads();
    if (tid == 0) {
        float mn = fminf(fminf(smin[0], smin[1]), fminf(smin[2], smin[3]));
        float mx = fmaxf(fmaxf(smax[0], smax[1]), fmaxf(smax[2], smax[3]));
        atomicMin(&minmax[2 * b], __float_as_uint(mn));
        atomicMax(&minmax[2 * b + 1], __float_as_uint(mx));
    }
}

__global__ __launch_bounds__(256) void hist_kernel(const float* __restrict__ blurred,
                                                   const unsigned* __restrict__ minmax,
                                                   unsigned* __restrict__ hist) {
    #pragma clang fp contract(off)
    const int b = blockIdx.y;
    __shared__ unsigned sh[256];
    sh[threadIdx.x] = 0u;
    __syncthreads();
    const float lo = __uint_as_float(minmax[2 * b]);
    const float hi = __uint_as_float(minmax[2 * b + 1]);
    const float width = (hi - lo) * 0.00390625f;      // /256 exact (pow2)
    const float denom = fmaxf(width, 1e-12f);
    const float4* img = (const float4*)(blurred + (size_t)b * 262144);
    for (int i = blockIdx.x * blockDim.x + threadIdx.x; i < 65536; i += gridDim.x * blockDim.x) {
        float4 v = img[i];
        int i0 = min(max((int)floorf((v.x - lo) / denom), 0), 255);
        int i1 = min(max((int)floorf((v.y - lo) / denom), 0), 255);
        int i2 = min(max((int)floorf((v.z - lo) / denom), 0), 255);
        int i3 = min(max((int)floorf((v.w - lo) / denom), 0), 255);
        atomicAdd(&sh[i0], 1u);
        atomicAdd(&sh[i1], 1u);
        atomicAdd(&sh[i2], 1u);
        atomicAdd(&sh[i3], 1u);
    }
    __syncthreads();
    atomicAdd(&hist[b * 256 + threadIdx.x], sh[threadIdx.x]);
}

// Sequential f32 cumsums (np.cumsum order); strict > argmax = first occurrence.
__global__ __launch_bounds__(256) void otsu_kernel(const unsigned* __restrict__ hist,
                                                   const unsigned* __restrict__ minmax,
                                                   float* __restrict__ t) {
    #pragma clang fp contract(off)
    __shared__ float counts[256], centers[256], w1[256], w2[256], cs[256], rcs[256];
    const int b = blockIdx.x, tid = threadIdx.x;
    const float lo = __uint_as_float(minmax[2 * b]);
    const float hi = __uint_as_float(minmax[2 * b + 1]);
    const float width = (hi - lo) * 0.00390625f;
    counts[tid] = (float)hist[b * 256 + tid];
    centers[tid] = lo + ((float)tid + 0.5f) * width;
    __syncthreads();
    if (tid == 0) {
        float a = 0.f;
        for (int i = 0; i < 256; ++i) { a = a + counts[i]; w1[i] = a; }
        a = 0.f;
        for (int i = 255; i >= 0; --i) { a = a + counts[i]; w2[i] = a; }
        a = 0.f;
        for (int i = 0; i < 256; ++i) { a = a + counts[i] * centers[i]; cs[i] = a; }
        a = 0.f;
        for (int i = 255; i >= 0; --i) { a = a + counts[i] * centers[i]; rcs[i] = a; }
        float best = -1e30f; int bi = 0;
        for (int i = 0; i < 255; ++i) {
            float m1 = cs[i] / fmaxf(w1[i], 1e-12f);
            float m2 = rcs[i + 1] / fmaxf(w2[i + 1], 1e-12f);
            float d = m1 - m2;
            float v = (w1[i] * w2[i + 1]) * (d * d);
            if (v > best) { best = v; bi = i; }
        }
        t[b] = centers[bi];
    }
}

__global__ __launch_bounds__(256) void final_kernel(const float* __restrict__ x,
                                                    const float* __restrict__ blurred,
                                                    const float* __restrict__ tarr,
                                                    float* __restrict__ out, int total4) {
    #pragma clang fp contract(off)
    int i = blockIdx.x * 256 + threadIdx.x;
    if (i >= total4) return;
    int b = i >> 16;
    int p = i & 65535;
    float tb = tarr[b];
    float4 bl = ((const float4*)(blurred + (size_t)b * 262144))[p];
    float4 m;
    m.x = (bl.x > tb) ? 1.0f : bl.x;
    m.y = (bl.y > tb) ? 1.0f : bl.y;
    m.z = (bl.z > tb) ? 1.0f : bl.z;
    m.w = (bl.w > tb) ? 1.0f : bl.w;
    const float4* xim = (const float4*)(x + (size_t)b * 4 * 262144);
    float4* oim = (float4*)(out + (size_t)b * 3 * 262144);
#pragma unroll
    for (int c = 0; c < 3; ++c) {
        float4 rgb = xim[(size_t)(c + 1) * 65536 + p];
        float4 o;
        o.x = fminf(fmaxf(m.x * rgb.x + (1.0f - m.x), 0.f), 1.f);
        o.y = fminf(fmaxf(m.y * rgb.y + (1.0f - m.y), 0.f), 1.f);
        o.z = fminf(fmaxf(m.z * rgb.z + (1.0f - m.z), 0.f), 1.f);
        o.w = fminf(fmaxf(m.w * rgb.w + (1.0f - m.w), 0.f), 1.f);
        oim[(size_t)c * 65536 + p] = o;
    }
}

extern "C" void kernel_launch(void* const* d_in, const int* in_sizes, int n_in,
                              void* d_out, int out_size, void* d_ws, size_t ws_size,
                              hipStream_t stream) {
    const float* x = (const float*)d_in[0];
    float* out = (float*)d_out;
    const int nimg = in_sizes[0] / (4 * 262144);   // 32 images of 4x512x512

    float* blurred = (float*)d_ws;                                  // nimg*262144 floats
    unsigned* hist = (unsigned*)((char*)d_ws + (size_t)nimg * 262144 * 4);
    unsigned* minmax = hist + (size_t)nimg * 256;
    float* t = (float*)(minmax + (size_t)nimg * 2);

    // Weights, numpy-f32-mirror:
    //   k[i] = (f32) correctly-rounded exp at exact inputs {0,-0.5,-2,-4.5,-8},
    //   s = np.sum pairwise order for n=9:
    //     ((k0+k1)+(k2+k3))+((k4+k5)+(k6+k7)) then += k8,
    //   w = k/s in f32.
    GaussW gw;
    float kk[9];
    for (int i = 0; i < 9; ++i) {
        double d = (double)(i - 4);
        kk[i] = (float)exp(-0.5 * d * d);
    }
    float s = ((kk[0] + kk[1]) + (kk[2] + kk[3])) + ((kk[4] + kk[5]) + (kk[6] + kk[7]));
    s = s + kk[8];
    for (int i = 0; i < 9; ++i) gw.w[i] = kk[i] / s;

    init_kernel<<<(nimg * 256 + 255) / 256, 256, 0, stream>>>(hist, minmax, nimg);
    dim3 bgrid(8, 8, nimg);
    blur_kernel<<<bgrid, 256, 0, stream>>>(x, blurred, minmax, gw);
    dim3 hgrid(64, nimg);
    hist_kernel<<<hgrid, 256, 0, stream>>>(blurred, minmax, hist);
    otsu_kernel<<<nimg, 256, 0, stream>>>(hist, minmax, t);
    int total4 = nimg * 65536;
    final_kernel<<<(total4 + 255) / 256, 256, 0, stream>>>(x, blurred, t, out, total4);
}

// Round 9
// 257.789 us; speedup vs baseline: 1.2072x; 1.2072x over previous
//
#include <hip/hip_runtime.h>
#include <math.h>

// Bit-matches a dtype-faithful numpy float32 mirror of the jax reference
// (proven r8): no FMA, numpy pairwise_sum tap order, sequential f32 cumsums,
// first-occurrence argmax. DECISION-PATH FP ORDER IS FROZEN — perf work only
// via exact-order-preserving restructuring (min/max are exact & order-free;
// cumsum batching keeps the identical add sequence; argmax parallelized with
// strict->-else-smaller-index semantics).
#pragma clang fp contract(off)

struct GaussW { float w[9]; };

// thermal = clip(x0*0.5+0.5); separable 9-tap Gaussian (edge clamp), numpy
// pairwise tap order; per-block min/max partials (no atomics); zeroes hist.
__global__ __launch_bounds__(256) void blur_kernel(const float* __restrict__ x,
                                                   float* __restrict__ blurred,
                                                   float* __restrict__ pmin,
                                                   float* __restrict__ pmax,
                                                   unsigned* __restrict__ hist, GaussW gw) {
    #pragma clang fp contract(off)
    __shared__ float s_in[72][72];   // rows r0-4..r0+67, cols c0-4..c0+67
    __shared__ float s_vb[64][72];   // vertically blurred
    const int tid = threadIdx.x;
    const int b = blockIdx.z;
    const int r0 = blockIdx.y * 64, c0 = blockIdx.x * 64;
    if (blockIdx.x == 0 && blockIdx.y == 0) hist[b * 256 + tid] = 0u;
    const float* img0 = x + (size_t)b * 4 * 262144;

    for (int i = tid; i < 72 * 72; i += 256) {
        int r = i / 72, c = i - r * 72;
        int gr = min(max(r0 + r - 4, 0), 511);
        int gc = min(max(c0 + c - 4, 0), 511);
        float v = img0[gr * 512 + gc];
        s_in[r][c] = fminf(fmaxf(v * 0.5f + 0.5f, 0.0f), 1.0f);
    }
    __syncthreads();
    for (int i = tid; i < 64 * 72; i += 256) {
        int r = i / 72, c = i - r * 72;
        float q0 = s_in[r + 0][c] * gw.w[0];
        float q1 = s_in[r + 1][c] * gw.w[1];
        float q2 = s_in[r + 2][c] * gw.w[2];
        float q3 = s_in[r + 3][c] * gw.w[3];
        float q4 = s_in[r + 4][c] * gw.w[4];
        float q5 = s_in[r + 5][c] * gw.w[5];
        float q6 = s_in[r + 6][c] * gw.w[6];
        float q7 = s_in[r + 7][c] * gw.w[7];
        float q8 = s_in[r + 8][c] * gw.w[8];
        float acc = ((q0 + q1) + (q2 + q3)) + ((q4 + q5) + (q6 + q7));
        acc = acc + q8;
        s_vb[r][c] = acc;
    }
    __syncthreads();
    float lmin = 1e30f, lmax = -1e30f;
    float* bimg = blurred + (size_t)b * 262144;
    for (int i = tid; i < 64 * 64; i += 256) {
        int r = i >> 6, c = i & 63;
        float q0 = s_vb[r][c + 0] * gw.w[0];
        float q1 = s_vb[r][c + 1] * gw.w[1];
        float q2 = s_vb[r][c + 2] * gw.w[2];
        float q3 = s_vb[r][c + 3] * gw.w[3];
        float q4 = s_vb[r][c + 4] * gw.w[4];
        float q5 = s_vb[r][c + 5] * gw.w[5];
        float q6 = s_vb[r][c + 6] * gw.w[6];
        float q7 = s_vb[r][c + 7] * gw.w[7];
        float q8 = s_vb[r][c + 8] * gw.w[8];
        float acc = ((q0 + q1) + (q2 + q3)) + ((q4 + q5) + (q6 + q7));
        acc = acc + q8;
        bimg[(r0 + r) * 512 + (c0 + c)] = acc;
        lmin = fminf(lmin, acc);
        lmax = fmaxf(lmax, acc);
    }
    for (int off = 32; off >= 1; off >>= 1) {
        lmin = fminf(lmin, __shfl_down(lmin, off));
        lmax = fmaxf(lmax, __shfl_down(lmax, off));
    }
    __shared__ float smin[4], smax[4];
    int wave = tid >> 6, lane = tid & 63;
    if (lane == 0) { smin[wave] = lmin; smax[wave] = lmax; }
    __syncthreads();
    if (tid == 0) {
        float mn = fminf(fminf(smin[0], smin[1]), fminf(smin[2], smin[3]));
        float mx = fmaxf(fmaxf(smax[0], smax[1]), fmaxf(smax[2], smax[3]));
        int bid = blockIdx.y * 8 + blockIdx.x;
        pmin[b * 64 + bid] = mn;
        pmax[b * 64 + bid] = mx;
    }
}

// Reduce the 64 min/max partials in-wave (exact, order-free), then bin.
__global__ __launch_bounds__(256) void hist_kernel(const float* __restrict__ blurred,
                                                   const float* __restrict__ pmin,
                                                   const float* __restrict__ pmax,
                                                   unsigned* __restrict__ hist) {
    #pragma clang fp contract(off)
    const int b = blockIdx.y;
    __shared__ unsigned sh[256];
    __shared__ float s_lo, s_hi;
    sh[threadIdx.x] = 0u;
    int wv = threadIdx.x >> 6, ln = threadIdx.x & 63;
    if (wv == 0) {
        float v = pmin[b * 64 + ln];
        for (int off = 32; off >= 1; off >>= 1) v = fminf(v, __shfl_down(v, off));
        if (ln == 0) s_lo = v;
    } else if (wv == 1) {
        float v = pmax[b * 64 + ln];
        for (int off = 32; off >= 1; off >>= 1) v = fmaxf(v, __shfl_down(v, off));
        if (ln == 0) s_hi = v;
    }
    __syncthreads();
    const float lo = s_lo, hi = s_hi;
    const float width = (hi - lo) * 0.00390625f;      // /256 exact (pow2)
    const float denom = fmaxf(width, 1e-12f);
    const float4* img = (const float4*)(blurred + (size_t)b * 262144);
    for (int i = blockIdx.x * 256 + threadIdx.x; i < 65536; i += gridDim.x * 256) {
        float4 v = img[i];
        int i0 = min(max((int)floorf((v.x - lo) / denom), 0), 255);
        int i1 = min(max((int)floorf((v.y - lo) / denom), 0), 255);
        int i2 = min(max((int)floorf((v.z - lo) / denom), 0), 255);
        int i3 = min(max((int)floorf((v.w - lo) / denom), 0), 255);
        atomicAdd(&sh[i0], 1u);
        atomicAdd(&sh[i1], 1u);
        atomicAdd(&sh[i2], 1u);
        atomicAdd(&sh[i3], 1u);
    }
    __syncthreads();
    unsigned cnt = sh[threadIdx.x];
    if (cnt) atomicAdd(&hist[b * 256 + threadIdx.x], cnt);
}

// 4 independent cumsums on 4 waves (identical sequential f32 order, LDS loads
// batched x8 for latency); wave-parallel argmax with np first-occurrence
// semantics (strict >, tie -> smaller index).
__global__ __launch_bounds__(256) void otsu_kernel(const unsigned* __restrict__ hist,
                                                   const float* __restrict__ pmin,
                                                   const float* __restrict__ pmax,
                                                   float* __restrict__ t) {
    #pragma clang fp contract(off)
    __shared__ float counts[256], centers[256], w1[256], w2[256], cs[256], rcs[256];
    __shared__ float s_lo, s_hi;
    const int b = blockIdx.x, tid = threadIdx.x;
    const int wv = tid >> 6, ln = tid & 63;
    if (wv == 0) {
        float v = pmin[b * 64 + ln];
        for (int off = 32; off >= 1; off >>= 1) v = fminf(v, __shfl_down(v, off));
        if (ln == 0) s_lo = v;
    } else if (wv == 1) {
        float v = pmax[b * 64 + ln];
        for (int off = 32; off >= 1; off >>= 1) v = fmaxf(v, __shfl_down(v, off));
        if (ln == 0) s_hi = v;
    }
    __syncthreads();
    const float lo = s_lo, hi = s_hi;
    const float width = (hi - lo) * 0.00390625f;
    counts[tid] = (float)hist[b * 256 + tid];
    centers[tid] = lo + ((float)tid + 0.5f) * width;
    __syncthreads();
    if (ln == 0) {
        if (wv == 0) {            // w1: ascending cumsum of counts
            float a = 0.f;
            for (int i0 = 0; i0 < 256; i0 += 8) {
                float c0 = counts[i0+0], c1 = counts[i0+1], c2 = counts[i0+2], c3 = counts[i0+3];
                float c4 = counts[i0+4], c5 = counts[i0+5], c6 = counts[i0+6], c7 = counts[i0+7];
                a = a + c0; w1[i0+0] = a; a = a + c1; w1[i0+1] = a;
                a = a + c2; w1[i0+2] = a; a = a + c3; w1[i0+3] = a;
                a = a + c4; w1[i0+4] = a; a = a + c5; w1[i0+5] = a;
                a = a + c6; w1[i0+6] = a; a = a + c7; w1[i0+7] = a;
            }
        } else if (wv == 1) {     // w2: descending cumsum of counts
            float a = 0.f;
            for (int i0 = 255; i0 >= 7; i0 -= 8) {
                float c0 = counts[i0-0], c1 = counts[i0-1], c2 = counts[i0-2], c3 = counts[i0-3];
                float c4 = counts[i0-4], c5 = counts[i0-5], c6 = counts[i0-6], c7 = counts[i0-7];
                a = a + c0; w2[i0-0] = a; a = a + c1; w2[i0-1] = a;
                a = a + c2; w2[i0-2] = a; a = a + c3; w2[i0-3] = a;
                a = a + c4; w2[i0-4] = a; a = a + c5; w2[i0-5] = a;
                a = a + c6; w2[i0-6] = a; a = a + c7; w2[i0-7] = a;
            }
        } else if (wv == 2) {     // cs: ascending cumsum of counts*centers
            float a = 0.f;
            for (int i0 = 0; i0 < 256; i0 += 8) {
                float q0 = counts[i0+0] * centers[i0+0], q1 = counts[i0+1] * centers[i0+1];
                float q2 = counts[i0+2] * centers[i0+2], q3 = counts[i0+3] * centers[i0+3];
                float q4 = counts[i0+4] * centers[i0+4], q5 = counts[i0+5] * centers[i0+5];
                float q6 = counts[i0+6] * centers[i0+6], q7 = counts[i0+7] * centers[i0+7];
                a = a + q0; cs[i0+0] = a; a = a + q1; cs[i0+1] = a;
                a = a + q2; cs[i0+2] = a; a = a + q3; cs[i0+3] = a;
                a = a + q4; cs[i0+4] = a; a = a + q5; cs[i0+5] = a;
                a = a + q6; cs[i0+6] = a; a = a + q7; cs[i0+7] = a;
            }
        } else {                  // rcs: descending cumsum of counts*centers
            float a = 0.f;
            for (int i0 = 255; i0 >= 7; i0 -= 8) {
                float q0 = counts[i0-0] * centers[i0-0], q1 = counts[i0-1] * centers[i0-1];
                float q2 = counts[i0-2] * centers[i0-2], q3 = counts[i0-3] * centers[i0-3];
                float q4 = counts[i0-4] * centers[i0-4], q5 = counts[i0-5] * centers[i0-5];
                float q6 = counts[i0-6] * centers[i0-6], q7 = counts[i0-7] * centers[i0-7];
                a = a + q0; rcs[i0-0] = a; a = a + q1; rcs[i0-1] = a;
                a = a + q2; rcs[i0-2] = a; a = a + q3; rcs[i0-3] = a;
                a = a + q4; rcs[i0-4] = a; a = a + q5; rcs[i0-5] = a;
                a = a + q6; rcs[i0-6] = a; a = a + q7; rcs[i0-7] = a;
            }
        }
    }
    __syncthreads();
    if (wv == 0) {
        float best = -1e30f; int bi = 0x7fffffff;
#pragma unroll
        for (int k = 0; k < 4; ++k) {
            int i = ln + 64 * k;
            if (i < 255) {
                float m1 = cs[i] / fmaxf(w1[i], 1e-12f);
                float m2 = rcs[i + 1] / fmaxf(w2[i + 1], 1e-12f);
                float d = m1 - m2;
                float v = (w1[i] * w2[i + 1]) * (d * d);
                if (v > best) { best = v; bi = i; }   // i ascends in-lane: strict > == first occurrence
            }
        }
        for (int off = 32; off >= 1; off >>= 1) {
            float ov = __shfl_down(best, off);
            int   oi = __shfl_down(bi, off);
            if (ov > best || (ov == best && oi < bi)) { best = ov; bi = oi; }
        }
        if (ln == 0) t[b] = centers[bi];
    }
}

__global__ __launch_bounds__(256) void final_kernel(const float* __restrict__ x,
                                                    const float* __restrict__ blurred,
                                                    const float* __restrict__ tarr,
                                                    float* __restrict__ out, int total4) {
    #pragma clang fp contract(off)
    int i = blockIdx.x * 256 + threadIdx.x;
    if (i >= total4) return;
    int b = i >> 16;
    int p = i & 65535;
    float tb = tarr[b];
    float4 bl = ((const float4*)(blurred + (size_t)b * 262144))[p];
    float4 m;
    m.x = (bl.x > tb) ? 1.0f : bl.x;
    m.y = (bl.y > tb) ? 1.0f : bl.y;
    m.z = (bl.z > tb) ? 1.0f : bl.z;
    m.w = (bl.w > tb) ? 1.0f : bl.w;
    const float4* xim = (const float4*)(x + (size_t)b * 4 * 262144);
    float4* oim = (float4*)(out + (size_t)b * 3 * 262144);
#pragma unroll
    for (int c = 0; c < 3; ++c) {
        float4 rgb = xim[(size_t)(c + 1) * 65536 + p];
        float4 o;
        o.x = fminf(fmaxf(m.x * rgb.x + (1.0f - m.x), 0.f), 1.f);
        o.y = fminf(fmaxf(m.y * rgb.y + (1.0f - m.y), 0.f), 1.f);
        o.z = fminf(fmaxf(m.z * rgb.z + (1.0f - m.z), 0.f), 1.f);
        o.w = fminf(fmaxf(m.w * rgb.w + (1.0f - m.w), 0.f), 1.f);
        oim[(size_t)c * 65536 + p] = o;
    }
}

extern "C" void kernel_launch(void* const* d_in, const int* in_sizes, int n_in,
                              void* d_out, int out_size, void* d_ws, size_t ws_size,
                              hipStream_t stream) {
    const float* x = (const float*)d_in[0];
    float* out = (float*)d_out;
    const int nimg = in_sizes[0] / (4 * 262144);   // 32 images of 4x512x512

    float* blurred = (float*)d_ws;                                   // nimg*262144 f32
    unsigned* hist = (unsigned*)(blurred + (size_t)nimg * 262144);   // nimg*256 u32
    float* pmin = (float*)(hist + (size_t)nimg * 256);               // nimg*64
    float* pmax = pmin + (size_t)nimg * 64;                          // nimg*64
    float* t = pmax + (size_t)nimg * 64;                             // nimg

    // Weights, numpy-f32-mirror (frozen):
    //   k[i] = (f32) CR exp at exact inputs, s = np.sum pairwise order for n=9,
    //   w = k/s in f32.
    GaussW gw;
    float kk[9];
    for (int i = 0; i < 9; ++i) {
        double d = (double)(i - 4);
        kk[i] = (float)exp(-0.5 * d * d);
    }
    float s = ((kk[0] + kk[1]) + (kk[2] + kk[3])) + ((kk[4] + kk[5]) + (kk[6] + kk[7]));
    s = s + kk[8];
    for (int i = 0; i < 9; ++i) gw.w[i] = kk[i] / s;

    dim3 bgrid(8, 8, nimg);
    blur_kernel<<<bgrid, 256, 0, stream>>>(x, blurred, pmin, pmax, hist, gw);
    dim3 hgrid(16, nimg);
    hist_kernel<<<hgrid, 256, 0, stream>>>(blurred, pmin, pmax, hist);
    otsu_kernel<<<nimg, 256, 0, stream>>>(hist, pmin, pmax, t);
    int total4 = nimg * 65536;
    final_kernel<<<(total4 + 255) / 256, 256, 0, stream>>>(x, blurred, t, out, total4);
}

// Round 10
// 254.019 us; speedup vs baseline: 1.2252x; 1.0148x over previous
//
#include <hip/hip_runtime.h>
#include <math.h>

// Bit-matches a dtype-faithful numpy float32 mirror of the jax reference
// (proven r8): no FMA, numpy pairwise_sum tap order, sequential f32 cumsums,
// first-occurrence argmax. DECISION-PATH FP ORDER IS FROZEN — perf work only
// via exact-order-preserving restructuring. r10: blur strip-mining (shared
// tap loads, identical per-output FP tree), 8-copy LDS histogram.
#pragma clang fp contract(off)

struct GaussW { float w[9]; };

// thermal = clip(x0*0.5+0.5); separable 9-tap Gaussian (edge clamp), numpy
// pairwise tap order; per-block min/max partials; zeroes hist.
__global__ __launch_bounds__(256) void blur_kernel(const float* __restrict__ x,
                                                   float* __restrict__ blurred,
                                                   float* __restrict__ pmin,
                                                   float* __restrict__ pmax,
                                                   unsigned* __restrict__ hist, GaussW gw) {
    #pragma clang fp contract(off)
    __shared__ float s_in[72][72];   // rows r0-4..r0+67, cols c0-4..c0+67
    __shared__ float s_vb[64][72];   // vertically blurred
    const int tid = threadIdx.x;
    const int b = blockIdx.z;
    const int r0 = blockIdx.y * 64, c0 = blockIdx.x * 64;
    if (blockIdx.x == 0 && blockIdx.y == 0) hist[b * 256 + tid] = 0u;
    const float* img0 = x + (size_t)b * 4 * 262144;

    for (int i = tid; i < 72 * 72; i += 256) {
        int r = i / 72, c = i - r * 72;
        int gr = min(max(r0 + r - 4, 0), 511);
        int gc = min(max(c0 + c - 4, 0), 511);
        float v = img0[gr * 512 + gc];
        s_in[r][c] = fminf(fmaxf(v * 0.5f + 0.5f, 0.0f), 1.0f);
    }
    __syncthreads();
    // Vertical: 16 row-strips x 72 cols = 1152 strips; each strip = 4 outputs
    // sharing 12 column taps. Per-output FP tree identical to r8/r9.
    for (int i = tid; i < 1152; i += 256) {
        int sr = (i / 72) * 4, c = i % 72;
        float t0 = s_in[sr + 0][c], t1 = s_in[sr + 1][c], t2 = s_in[sr + 2][c];
        float t3 = s_in[sr + 3][c], t4 = s_in[sr + 4][c], t5 = s_in[sr + 5][c];
        float t6 = s_in[sr + 6][c], t7 = s_in[sr + 7][c], t8 = s_in[sr + 8][c];
        float t9 = s_in[sr + 9][c], t10 = s_in[sr + 10][c], t11 = s_in[sr + 11][c];
        {
            float q0 = t0 * gw.w[0], q1 = t1 * gw.w[1], q2 = t2 * gw.w[2], q3 = t3 * gw.w[3];
            float q4 = t4 * gw.w[4], q5 = t5 * gw.w[5], q6 = t6 * gw.w[6], q7 = t7 * gw.w[7];
            float acc = ((q0 + q1) + (q2 + q3)) + ((q4 + q5) + (q6 + q7));
            s_vb[sr + 0][c] = acc + t8 * gw.w[8];
        }
        {
            float q0 = t1 * gw.w[0], q1 = t2 * gw.w[1], q2 = t3 * gw.w[2], q3 = t4 * gw.w[3];
            float q4 = t5 * gw.w[4], q5 = t6 * gw.w[5], q6 = t7 * gw.w[6], q7 = t8 * gw.w[7];
            float acc = ((q0 + q1) + (q2 + q3)) + ((q4 + q5) + (q6 + q7));
            s_vb[sr + 1][c] = acc + t9 * gw.w[8];
        }
        {
            float q0 = t2 * gw.w[0], q1 = t3 * gw.w[1], q2 = t4 * gw.w[2], q3 = t5 * gw.w[3];
            float q4 = t6 * gw.w[4], q5 = t7 * gw.w[5], q6 = t8 * gw.w[6], q7 = t9 * gw.w[7];
            float acc = ((q0 + q1) + (q2 + q3)) + ((q4 + q5) + (q6 + q7));
            s_vb[sr + 2][c] = acc + t10 * gw.w[8];
        }
        {
            float q0 = t3 * gw.w[0], q1 = t4 * gw.w[1], q2 = t5 * gw.w[2], q3 = t6 * gw.w[3];
            float q4 = t7 * gw.w[4], q5 = t8 * gw.w[5], q6 = t9 * gw.w[6], q7 = t10 * gw.w[7];
            float acc = ((q0 + q1) + (q2 + q3)) + ((q4 + q5) + (q6 + q7));
            s_vb[sr + 3][c] = acc + t11 * gw.w[8];
        }
    }
    __syncthreads();
    // Horizontal: 64 rows x 16 col-strips; each strip = 4 outputs sharing 12
    // taps loaded as 3 aligned float4s. float4 coalesced global store.
    float lmin = 1e30f, lmax = -1e30f;
    float* bimg = blurred + (size_t)b * 262144;
    for (int i = tid; i < 1024; i += 256) {
        int r = i >> 4, cc = (i & 15) * 4;
        float4 va = *(const float4*)&s_vb[r][cc];
        float4 vb = *(const float4*)&s_vb[r][cc + 4];
        float4 vc = *(const float4*)&s_vb[r][cc + 8];
        float t0 = va.x, t1 = va.y, t2 = va.z, t3 = va.w;
        float t4 = vb.x, t5 = vb.y, t6 = vb.z, t7 = vb.w;
        float t8 = vc.x, t9 = vc.y, t10 = vc.z, t11 = vc.w;
        float4 o;
        {
            float q0 = t0 * gw.w[0], q1 = t1 * gw.w[1], q2 = t2 * gw.w[2], q3 = t3 * gw.w[3];
            float q4 = t4 * gw.w[4], q5 = t5 * gw.w[5], q6 = t6 * gw.w[6], q7 = t7 * gw.w[7];
            float acc = ((q0 + q1) + (q2 + q3)) + ((q4 + q5) + (q6 + q7));
            o.x = acc + t8 * gw.w[8];
        }
        {
            float q0 = t1 * gw.w[0], q1 = t2 * gw.w[1], q2 = t3 * gw.w[2], q3 = t4 * gw.w[3];
            float q4 = t5 * gw.w[4], q5 = t6 * gw.w[5], q6 = t7 * gw.w[6], q7 = t8 * gw.w[7];
            float acc = ((q0 + q1) + (q2 + q3)) + ((q4 + q5) + (q6 + q7));
            o.y = acc + t9 * gw.w[8];
        }
        {
            float q0 = t2 * gw.w[0], q1 = t3 * gw.w[1], q2 = t4 * gw.w[2], q3 = t5 * gw.w[3];
            float q4 = t6 * gw.w[4], q5 = t7 * gw.w[5], q6 = t8 * gw.w[6], q7 = t9 * gw.w[7];
            float acc = ((q0 + q1) + (q2 + q3)) + ((q4 + q5) + (q6 + q7));
            o.z = acc + t10 * gw.w[8];
        }
        {
            float q0 = t3 * gw.w[0], q1 = t4 * gw.w[1], q2 = t5 * gw.w[2], q3 = t6 * gw.w[3];
            float q4 = t7 * gw.w[4], q5 = t8 * gw.w[5], q6 = t9 * gw.w[6], q7 = t10 * gw.w[7];
            float acc = ((q0 + q1) + (q2 + q3)) + ((q4 + q5) + (q6 + q7));
            o.w = acc + t11 * gw.w[8];
        }
        *(float4*)&bimg[(size_t)(r0 + r) * 512 + (c0 + cc)] = o;
        lmin = fminf(fminf(fminf(lmin, o.x), fminf(o.y, o.z)), o.w);
        lmax = fmaxf(fmaxf(fmaxf(lmax, o.x), fmaxf(o.y, o.z)), o.w);
    }
    for (int off = 32; off >= 1; off >>= 1) {
        lmin = fminf(lmin, __shfl_down(lmin, off));
        lmax = fmaxf(lmax, __shfl_down(lmax, off));
    }
    __shared__ float smin[4], smax[4];
    int wave = tid >> 6, lane = tid & 63;
    if (lane == 0) { smin[wave] = lmin; smax[wave] = lmax; }
    __syncthreads();
    if (tid == 0) {
        float mn = fminf(fminf(smin[0], smin[1]), fminf(smin[2], smin[3]));
        float mx = fmaxf(fmaxf(smax[0], smax[1]), fmaxf(smax[2], smax[3]));
        int bid = blockIdx.y * 8 + blockIdx.x;
        pmin[b * 64 + bid] = mn;
        pmax[b * 64 + bid] = mx;
    }
}

// Reduce the 64 min/max partials in-wave (exact, order-free), then bin with
// 8-copy LDS sub-histograms (conflict degree /8; integer adds — exact).
__global__ __launch_bounds__(256) void hist_kernel(const float* __restrict__ blurred,
                                                   const float* __restrict__ pmin,
                                                   const float* __restrict__ pmax,
                                                   unsigned* __restrict__ hist) {
    #pragma clang fp contract(off)
    const int b = blockIdx.y;
    __shared__ unsigned sh[2048];    // [bin*8 + copy]
    __shared__ float s_lo, s_hi;
    for (int i = threadIdx.x; i < 2048; i += 256) sh[i] = 0u;
    int wv = threadIdx.x >> 6, ln = threadIdx.x & 63;
    if (wv == 0) {
        float v = pmin[b * 64 + ln];
        for (int off = 32; off >= 1; off >>= 1) v = fminf(v, __shfl_down(v, off));
        if (ln == 0) s_lo = v;
    } else if (wv == 1) {
        float v = pmax[b * 64 + ln];
        for (int off = 32; off >= 1; off >>= 1) v = fmaxf(v, __shfl_down(v, off));
        if (ln == 0) s_hi = v;
    }
    __syncthreads();
    const float lo = s_lo, hi = s_hi;
    const float width = (hi - lo) * 0.00390625f;      // /256 exact (pow2)
    const float denom = fmaxf(width, 1e-12f);
    const int copy = threadIdx.x & 7;
    const float4* img = (const float4*)(blurred + (size_t)b * 262144);
    for (int i = blockIdx.x * 256 + threadIdx.x; i < 65536; i += gridDim.x * 256) {
        float4 v = img[i];
        int i0 = min(max((int)floorf((v.x - lo) / denom), 0), 255);
        int i1 = min(max((int)floorf((v.y - lo) / denom), 0), 255);
        int i2 = min(max((int)floorf((v.z - lo) / denom), 0), 255);
        int i3 = min(max((int)floorf((v.w - lo) / denom), 0), 255);
        atomicAdd(&sh[i0 * 8 + copy], 1u);
        atomicAdd(&sh[i1 * 8 + copy], 1u);
        atomicAdd(&sh[i2 * 8 + copy], 1u);
        atomicAdd(&sh[i3 * 8 + copy], 1u);
    }
    __syncthreads();
    unsigned cnt = 0;
    int base = threadIdx.x * 8;
#pragma unroll
    for (int k = 0; k < 8; ++k) cnt += sh[base + k];
    if (cnt) atomicAdd(&hist[b * 256 + threadIdx.x], cnt);
}

// 4 independent cumsums on 4 waves (identical sequential f32 order, LDS loads
// batched x8); wave-parallel argmax with np first-occurrence semantics.
__global__ __launch_bounds__(256) void otsu_kernel(const unsigned* __restrict__ hist,
                                                   const float* __restrict__ pmin,
                                                   const float* __restrict__ pmax,
                                                   float* __restrict__ t) {
    #pragma clang fp contract(off)
    __shared__ float counts[256], centers[256], w1[256], w2[256], cs[256], rcs[256];
    __shared__ float s_lo, s_hi;
    const int b = blockIdx.x, tid = threadIdx.x;
    const int wv = tid >> 6, ln = tid & 63;
    if (wv == 0) {
        float v = pmin[b * 64 + ln];
        for (int off = 32; off >= 1; off >>= 1) v = fminf(v, __shfl_down(v, off));
        if (ln == 0) s_lo = v;
    } else if (wv == 1) {
        float v = pmax[b * 64 + ln];
        for (int off = 32; off >= 1; off >>= 1) v = fmaxf(v, __shfl_down(v, off));
        if (ln == 0) s_hi = v;
    }
    __syncthreads();
    const float lo = s_lo, hi = s_hi;
    const float width = (hi - lo) * 0.00390625f;
    counts[tid] = (float)hist[b * 256 + tid];
    centers[tid] = lo + ((float)tid + 0.5f) * width;
    __syncthreads();
    if (ln == 0) {
        if (wv == 0) {            // w1: ascending cumsum of counts
            float a = 0.f;
            for (int i0 = 0; i0 < 256; i0 += 8) {
                float c0 = counts[i0+0], c1 = counts[i0+1], c2 = counts[i0+2], c3 = counts[i0+3];
                float c4 = counts[i0+4], c5 = counts[i0+5], c6 = counts[i0+6], c7 = counts[i0+7];
                a = a + c0; w1[i0+0] = a; a = a + c1; w1[i0+1] = a;
                a = a + c2; w1[i0+2] = a; a = a + c3; w1[i0+3] = a;
                a = a + c4; w1[i0+4] = a; a = a + c5; w1[i0+5] = a;
                a = a + c6; w1[i0+6] = a; a = a + c7; w1[i0+7] = a;
            }
        } else if (wv == 1) {     // w2: descending cumsum of counts
            float a = 0.f;
            for (int i0 = 255; i0 >= 7; i0 -= 8) {
                float c0 = counts[i0-0], c1 = counts[i0-1], c2 = counts[i0-2], c3 = counts[i0-3];
                float c4 = counts[i0-4], c5 = counts[i0-5], c6 = counts[i0-6], c7 = counts[i0-7];
                a = a + c0; w2[i0-0] = a; a = a + c1; w2[i0-1] = a;
                a = a + c2; w2[i0-2] = a; a = a + c3; w2[i0-3] = a;
                a = a + c4; w2[i0-4] = a; a = a + c5; w2[i0-5] = a;
                a = a + c6; w2[i0-6] = a; a = a + c7; w2[i0-7] = a;
            }
        } else if (wv == 2) {     // cs: ascending cumsum of counts*centers
            float a = 0.f;
            for (int i0 = 0; i0 < 256; i0 += 8) {
                float q0 = counts[i0+0] * centers[i0+0], q1 = counts[i0+1] * centers[i0+1];
                float q2 = counts[i0+2] * centers[i0+2], q3 = counts[i0+3] * centers[i0+3];
                float q4 = counts[i0+4] * centers[i0+4], q5 = counts[i0+5] * centers[i0+5];
                float q6 = counts[i0+6] * centers[i0+6], q7 = counts[i0+7] * centers[i0+7];
                a = a + q0; cs[i0+0] = a; a = a + q1; cs[i0+1] = a;
                a = a + q2; cs[i0+2] = a; a = a + q3; cs[i0+3] = a;
                a = a + q4; cs[i0+4] = a; a = a + q5; cs[i0+5] = a;
                a = a + q6; cs[i0+6] = a; a = a + q7; cs[i0+7] = a;
            }
        } else {                  // rcs: descending cumsum of counts*centers
            float a = 0.f;
            for (int i0 = 255; i0 >= 7; i0 -= 8) {
                float q0 = counts[i0-0] * centers[i0-0], q1 = counts[i0-1] * centers[i0-1];
                float q2 = counts[i0-2] * centers[i0-2], q3 = counts[i0-3] * centers[i0-3];
                float q4 = counts[i0-4] * centers[i0-4], q5 = counts[i0-5] * centers[i0-5];
                float q6 = counts[i0-6] * centers[i0-6], q7 = counts[i0-7] * centers[i0-7];
                a = a + q0; rcs[i0-0] = a; a = a + q1; rcs[i0-1] = a;
                a = a + q2; rcs[i0-2] = a; a = a + q3; rcs[i0-3] = a;
                a = a + q4; rcs[i0-4] = a; a = a + q5; rcs[i0-5] = a;
                a = a + q6; rcs[i0-6] = a; a = a + q7; rcs[i0-7] = a;
            }
        }
    }
    __syncthreads();
    if (wv == 0) {
        float best = -1e30f; int bi = 0x7fffffff;
#pragma unroll
        for (int k = 0; k < 4; ++k) {
            int i = ln + 64 * k;
            if (i < 255) {
                float m1 = cs[i] / fmaxf(w1[i], 1e-12f);
                float m2 = rcs[i + 1] / fmaxf(w2[i + 1], 1e-12f);
                float d = m1 - m2;
                float v = (w1[i] * w2[i + 1]) * (d * d);
                if (v > best) { best = v; bi = i; }   // i ascends in-lane: strict > == first occurrence
            }
        }
        for (int off = 32; off >= 1; off >>= 1) {
            float ov = __shfl_down(best, off);
            int   oi = __shfl_down(bi, off);
            if (ov > best || (ov == best && oi < bi)) { best = ov; bi = oi; }
        }
        if (ln == 0) t[b] = centers[bi];
    }
}

__global__ __launch_bounds__(256) void final_kernel(const float* __restrict__ x,
                                                    const float* __restrict__ blurred,
                                                    const float* __restrict__ tarr,
                                                    float* __restrict__ out, int total4) {
    #pragma clang fp contract(off)
    int i = blockIdx.x * 256 + threadIdx.x;
    if (i >= total4) return;
    int b = i >> 16;
    int p = i & 65535;
    float tb = tarr[b];
    float4 bl = ((const float4*)(blurred + (size_t)b * 262144))[p];
    float4 m;
    m.x = (bl.x > tb) ? 1.0f : bl.x;
    m.y = (bl.y > tb) ? 1.0f : bl.y;
    m.z = (bl.z > tb) ? 1.0f : bl.z;
    m.w = (bl.w > tb) ? 1.0f : bl.w;
    const float4* xim = (const float4*)(x + (size_t)b * 4 * 262144);
    float4* oim = (float4*)(out + (size_t)b * 3 * 262144);
#pragma unroll
    for (int c = 0; c < 3; ++c) {
        float4 rgb = xim[(size_t)(c + 1) * 65536 + p];
        float4 o;
        o.x = fminf(fmaxf(m.x * rgb.x + (1.0f - m.x), 0.f), 1.f);
        o.y = fminf(fmaxf(m.y * rgb.y + (1.0f - m.y), 0.f), 1.f);
        o.z = fminf(fmaxf(m.z * rgb.z + (1.0f - m.z), 0.f), 1.f);
        o.w = fminf(fmaxf(m.w * rgb.w + (1.0f - m.w), 0.f), 1.f);
        oim[(size_t)c * 65536 + p] = o;
    }
}

extern "C" void kernel_launch(void* const* d_in, const int* in_sizes, int n_in,
                              void* d_out, int out_size, void* d_ws, size_t ws_size,
                              hipStream_t stream) {
    const float* x = (const float*)d_in[0];
    float* out = (float*)d_out;
    const int nimg = in_sizes[0] / (4 * 262144);   // 32 images of 4x512x512

    float* blurred = (float*)d_ws;                                   // nimg*262144 f32
    unsigned* hist = (unsigned*)(blurred + (size_t)nimg * 262144);   // nimg*256 u32
    float* pmin = (float*)(hist + (size_t)nimg * 256);               // nimg*64
    float* pmax = pmin + (size_t)nimg * 64;                          // nimg*64
    float* t = pmax + (size_t)nimg * 64;                             // nimg

    // Weights, numpy-f32-mirror (frozen): CR-f32 exp at exact inputs,
    // np.sum pairwise order for n=9, w = k/s in f32.
    GaussW gw;
    float kk[9];
    for (int i = 0; i < 9; ++i) {
        double d = (double)(i - 4);
        kk[i] = (float)exp(-0.5 * d * d);
    }
    float s = ((kk[0] + kk[1]) + (kk[2] + kk[3])) + ((kk[4] + kk[5]) + (kk[6] + kk[7]));
    s = s + kk[8];
    for (int i = 0; i < 9; ++i) gw.w[i] = kk[i] / s;

    dim3 bgrid(8, 8, nimg);
    blur_kernel<<<bgrid, 256, 0, stream>>>(x, blurred, pmin, pmax, hist, gw);
    dim3 hgrid(16, nimg);
    hist_kernel<<<hgrid, 256, 0, stream>>>(blurred, pmin, pmax, hist);
    otsu_kernel<<<nimg, 256, 0, stream>>>(hist, pmin, pmax, t);
    int total4 = nimg * 65536;
    final_kernel<<<(total4 + 255) / 256, 256, 0, stream>>>(x, blurred, t, out, total4);
}